// Round 1
// baseline (80.081 us; speedup 1.0000x reference)
//
#include <hip/hip_runtime.h>
#include <math.h>

#define N_LAYERS 2

typedef float vfloat4 __attribute__((ext_vector_type(4)));  // native vec for nontemporal store

// Apply RX mixing [[c, -i s],[-i s, c]] to complex pair (a,b); each float2 = (re, im).
__device__ __forceinline__ void rx_pair(float2& a, float2& b, float c, float s) {
    float2 na = make_float2(fmaf(c, a.x,  s * b.y), fmaf(c, a.y, -s * b.x));
    float2 nb = make_float2(fmaf(s, a.y,  c * b.x), fmaf(-s, a.x, c * b.y));
    a = na; b = nb;
}

// Build the fixed layer unitary U (4x4 complex), form M = U^dag P0 U, fold the
// initial-state phases (1,-i,-i,-1) into a real symmetric N, then collapse onto
// the (1,cosX0,sinX0) x (1,cosX1,sinX1) bilinear basis -> 9 floats K.
// out(x0,x1) = [1,cos x0,sin x0] . K . [1,cos x1,sin x1]^T
__device__ void compute_K(const float* __restrict__ w, float* __restrict__ K) {
    float2 U[4][4];  // U[col][row]
    for (int j = 0; j < 4; ++j)
        for (int r = 0; r < 4; ++r)
            U[j][r] = make_float2(j == r ? 1.f : 0.f, 0.f);

    for (int l = 0; l < N_LAYERS; ++l) {
        float t0 = 0.5f * w[2 * l + 0];
        float t1 = 0.5f * w[2 * l + 1];
        float c0 = __cosf(t0), s0 = __sinf(t0);
        float c1 = __cosf(t1), s1 = __sinf(t1);
        for (int j = 0; j < 4; ++j) {
            rx_pair(U[j][0], U[j][2], c0, s0);   // RX q0: mixes (0,2),(1,3)
            rx_pair(U[j][1], U[j][3], c0, s0);
            rx_pair(U[j][0], U[j][1], c1, s1);   // RX q1: mixes (0,1),(2,3)
            rx_pair(U[j][2], U[j][3], c1, s1);
            float2 tmp = U[j][2]; U[j][2] = U[j][3]; U[j][3] = tmp;  // CNOT
        }
    }

    float Mre[4][4], Mim[4][4];
    for (int j = 0; j < 4; ++j)
        for (int k = 0; k < 4; ++k) {
            float re = 0.f, im = 0.f;
            for (int m = 0; m < 2; ++m) {   // P0 projects onto rows 0,1
                re += U[j][m].x * U[k][m].x + U[j][m].y * U[k][m].y;
                im += U[j][m].x * U[k][m].y - U[j][m].y * U[k][m].x;
            }
            Mre[j][k] = re; Mim[j][k] = im;
        }

    float N00 = Mre[0][0], N11 = Mre[1][1], N22 = Mre[2][2], N33 = Mre[3][3];
    float N01 = Mim[0][1], N23 = Mim[2][3], N02 = Mim[0][2], N13 = Mim[1][3];
    float N03 = -Mre[0][3], N12 = Mre[1][2];

    K[0] = 0.25f * (N00 + N11 + N22 + N33);  // 1
    K[1] = 0.25f * (N00 - N11 + N22 - N33);  // X1
    K[2] = 0.50f * (N01 + N23);              // S1
    K[3] = 0.25f * (N00 + N11 - N22 - N33);  // X0
    K[4] = 0.25f * (N00 - N11 - N22 + N33);  // X0*X1
    K[5] = 0.50f * (N01 - N23);              // X0*S1
    K[6] = 0.50f * (N02 + N13);              // S0
    K[7] = 0.50f * (N02 - N13);              // S0*X1
    K[8] = 0.50f * (N03 + N12);              // S0*S1
}

// Tiny one-wave kernel: compute the 9 bilinear coefficients into workspace.
// Keeps the ~450-instr serial unitary evolution (and its VGPR footprint)
// OUT of the streaming kernel entirely.
__global__ __launch_bounds__(64) void qnet_coef_kernel(const float* __restrict__ w,
                                                       float* __restrict__ K) {
    if (threadIdx.x == 0) {
        float Kl[9];
        compute_K(w, Kl);
        #pragma unroll
        for (int j = 0; j < 9; ++j) K[j] = Kl[j];
    }
}

__device__ __forceinline__ float qnet_eval1(float x0, float x1,
                                            float k0, float k1, float k2,
                                            float k3, float k4, float k5,
                                            float k6, float k7, float k8) {
    float X0, S0, X1, S1;
    __sincosf(x0, &S0, &X0);   // one range reduction for both sin & cos
    __sincosf(x1, &S1, &X1);
    float t0 = fmaf(k2, S1, fmaf(k1, X1, k0));
    float t1 = fmaf(k5, S1, fmaf(k4, X1, k3));
    float t2 = fmaf(k8, S1, fmaf(k7, X1, k6));
    return fmaf(S0, t2, fmaf(X0, t1, t0));
}

// Streaming eval kernel: no LDS, no barrier, K read as wave-uniform scalars
// (s_load), 8 samples per thread = 4x dwordx4 loads in flight + 2x dwordx4
// nontemporal stores.
__global__ __launch_bounds__(256, 4) void qnet_eval_kernel(
    const float4* __restrict__ x, const float* __restrict__ Kg,
    vfloat4* __restrict__ out, int nquads) {  // nquads = #samples/4 (one out-float4 each)
    const float k0 = Kg[0], k1 = Kg[1], k2 = Kg[2],
                k3 = Kg[3], k4 = Kg[4], k5 = Kg[5],
                k6 = Kg[6], k7 = Kg[7], k8 = Kg[8];

    int i = blockIdx.x * blockDim.x + threadIdx.x;
    int q0 = 2 * i;                       // this thread owns out quads q0, q0+1
    if (q0 + 1 < nquads) {
        float4 xa = x[2 * q0 + 0];
        float4 xb = x[2 * q0 + 1];
        float4 xc = x[2 * q0 + 2];
        float4 xd = x[2 * q0 + 3];
        vfloat4 r0, r1;
        r0.x = qnet_eval1(xa.x, xa.y, k0, k1, k2, k3, k4, k5, k6, k7, k8);
        r0.y = qnet_eval1(xa.z, xa.w, k0, k1, k2, k3, k4, k5, k6, k7, k8);
        r0.z = qnet_eval1(xb.x, xb.y, k0, k1, k2, k3, k4, k5, k6, k7, k8);
        r0.w = qnet_eval1(xb.z, xb.w, k0, k1, k2, k3, k4, k5, k6, k7, k8);
        r1.x = qnet_eval1(xc.x, xc.y, k0, k1, k2, k3, k4, k5, k6, k7, k8);
        r1.y = qnet_eval1(xc.z, xc.w, k0, k1, k2, k3, k4, k5, k6, k7, k8);
        r1.z = qnet_eval1(xd.x, xd.y, k0, k1, k2, k3, k4, k5, k6, k7, k8);
        r1.w = qnet_eval1(xd.z, xd.w, k0, k1, k2, k3, k4, k5, k6, k7, k8);
        __builtin_nontemporal_store(r0, &out[q0 + 0]);
        __builtin_nontemporal_store(r1, &out[q0 + 1]);
    } else if (q0 < nquads) {             // odd tail quad
        float4 xa = x[2 * q0 + 0];
        float4 xb = x[2 * q0 + 1];
        vfloat4 r0;
        r0.x = qnet_eval1(xa.x, xa.y, k0, k1, k2, k3, k4, k5, k6, k7, k8);
        r0.y = qnet_eval1(xa.z, xa.w, k0, k1, k2, k3, k4, k5, k6, k7, k8);
        r0.z = qnet_eval1(xb.x, xb.y, k0, k1, k2, k3, k4, k5, k6, k7, k8);
        r0.w = qnet_eval1(xb.z, xb.w, k0, k1, k2, k3, k4, k5, k6, k7, k8);
        __builtin_nontemporal_store(r0, &out[q0]);
    }
}

extern "C" void kernel_launch(void* const* d_in, const int* in_sizes, int n_in,
                              void* d_out, int out_size, void* d_ws, size_t ws_size,
                              hipStream_t stream) {
    const float* x = (const float*)d_in[0];    // [B, 2] float32
    const float* w = (const float*)d_in[1];    // [N_LAYERS, 2] float32
    float* K = (float*)d_ws;                   // 9 floats of workspace

    qnet_coef_kernel<<<1, 64, 0, stream>>>(w, K);

    int nquads = in_sizes[0] / 8;              // in_sizes[0] = #floats = 2*B; quad = 4 samples
    int nthreads = (nquads + 1) / 2;           // 8 samples per thread
    int blocks = (nthreads + 255) / 256;
    qnet_eval_kernel<<<blocks, 256, 0, stream>>>(
        (const float4*)x, K, (vfloat4*)d_out, nquads);
}

// Round 2
// 78.304 us; speedup vs baseline: 1.0227x; 1.0227x over previous
//
#include <hip/hip_runtime.h>
#include <math.h>

#define N_LAYERS 2

typedef float vfloat4 __attribute__((ext_vector_type(4)));  // native vec for nontemporal store

// Apply RX mixing [[c, -i s],[-i s, c]] to complex pair (a,b); each float2 = (re, im).
__device__ __forceinline__ void rx_pair(float2& a, float2& b, float c, float s) {
    float2 na = make_float2(fmaf(c, a.x,  s * b.y), fmaf(c, a.y, -s * b.x));
    float2 nb = make_float2(fmaf(s, a.y,  c * b.x), fmaf(-s, a.x, c * b.y));
    a = na; b = nb;
}

// Build the fixed layer unitary U (4x4 complex), form M = U^dag P0 U, fold the
// initial-state phases (1,-i,-i,-1) into a real symmetric N, then collapse onto
// the (1,cosX0,sinX0) x (1,cosX1,sinX1) bilinear basis -> 9 floats K.
// out(x0,x1) = [1,cos x0,sin x0] . K . [1,cos x1,sin x1]^T
__device__ void compute_K(const float* __restrict__ w, float* __restrict__ K) {
    float2 U[4][4];  // U[col][row]
    for (int j = 0; j < 4; ++j)
        for (int r = 0; r < 4; ++r)
            U[j][r] = make_float2(j == r ? 1.f : 0.f, 0.f);

    for (int l = 0; l < N_LAYERS; ++l) {
        float t0 = 0.5f * w[2 * l + 0];
        float t1 = 0.5f * w[2 * l + 1];
        float c0 = __cosf(t0), s0 = __sinf(t0);
        float c1 = __cosf(t1), s1 = __sinf(t1);
        for (int j = 0; j < 4; ++j) {
            rx_pair(U[j][0], U[j][2], c0, s0);   // RX q0: mixes (0,2),(1,3)
            rx_pair(U[j][1], U[j][3], c0, s0);
            rx_pair(U[j][0], U[j][1], c1, s1);   // RX q1: mixes (0,1),(2,3)
            rx_pair(U[j][2], U[j][3], c1, s1);
            float2 tmp = U[j][2]; U[j][2] = U[j][3]; U[j][3] = tmp;  // CNOT
        }
    }

    float Mre[4][4], Mim[4][4];
    for (int j = 0; j < 4; ++j)
        for (int k = 0; k < 4; ++k) {
            float re = 0.f, im = 0.f;
            for (int m = 0; m < 2; ++m) {   // P0 projects onto rows 0,1
                re += U[j][m].x * U[k][m].x + U[j][m].y * U[k][m].y;
                im += U[j][m].x * U[k][m].y - U[j][m].y * U[k][m].x;
            }
            Mre[j][k] = re; Mim[j][k] = im;
        }

    float N00 = Mre[0][0], N11 = Mre[1][1], N22 = Mre[2][2], N33 = Mre[3][3];
    float N01 = Mim[0][1], N23 = Mim[2][3], N02 = Mim[0][2], N13 = Mim[1][3];
    float N03 = -Mre[0][3], N12 = Mre[1][2];

    K[0] = 0.25f * (N00 + N11 + N22 + N33);  // 1
    K[1] = 0.25f * (N00 - N11 + N22 - N33);  // X1
    K[2] = 0.50f * (N01 + N23);              // S1
    K[3] = 0.25f * (N00 + N11 - N22 - N33);  // X0
    K[4] = 0.25f * (N00 - N11 - N22 + N33);  // X0*X1
    K[5] = 0.50f * (N01 - N23);              // X0*S1
    K[6] = 0.50f * (N02 + N13);              // S0
    K[7] = 0.50f * (N02 - N13);              // S0*X1
    K[8] = 0.50f * (N03 + N12);              // S0*S1
}

__device__ __forceinline__ float qnet_eval1(float x0, float x1,
                                            float k0, float k1, float k2,
                                            float k3, float k4, float k5,
                                            float k6, float k7, float k8) {
    float X0, S0, X1, S1;
    __sincosf(x0, &S0, &X0);   // one range reduction feeds both v_sin and v_cos
    __sincosf(x1, &S1, &X1);
    float t0 = fmaf(k2, S1, fmaf(k1, X1, k0));
    float t1 = fmaf(k5, S1, fmaf(k4, X1, k3));
    float t2 = fmaf(k8, S1, fmaf(k7, X1, k6));
    return fmaf(S0, t2, fmaf(X0, t1, t0));
}

// Fused single-launch kernel: 8 samples per thread. The four dwordx4 loads are
// issued BEFORE the K-compute barrier so thread 0's ~450-instr serial unitary
// evolution hides under global-load latency. One launch total (the R1 split
// into coef+eval kernels cost +2.8 us of serial-launch overhead).
__global__ __launch_bounds__(256) void qnet_fused_kernel(
    const float4* __restrict__ x, const float* __restrict__ w,
    vfloat4* __restrict__ out, int nquads) {  // nquads = #samples/4 (one out-float4 each)
    int i = blockIdx.x * blockDim.x + threadIdx.x;
    int q0 = 2 * i;                           // this thread owns out quads q0, q0+1
    bool full = (q0 + 1 < nquads);
    bool tail = (q0 < nquads);

    float4 xa, xb, xc, xd;
    if (tail) {                               // issue loads before the barrier
        xa = x[2 * q0 + 0];
        xb = x[2 * q0 + 1];
    }
    if (full) {
        xc = x[2 * q0 + 2];
        xd = x[2 * q0 + 3];
    }

    __shared__ float Ks[9];
    if (threadIdx.x == 0) compute_K(w, Ks);
    __syncthreads();

    float k0 = Ks[0], k1 = Ks[1], k2 = Ks[2];
    float k3 = Ks[3], k4 = Ks[4], k5 = Ks[5];
    float k6 = Ks[6], k7 = Ks[7], k8 = Ks[8];

    if (full) {
        vfloat4 r0, r1;
        r0.x = qnet_eval1(xa.x, xa.y, k0, k1, k2, k3, k4, k5, k6, k7, k8);
        r0.y = qnet_eval1(xa.z, xa.w, k0, k1, k2, k3, k4, k5, k6, k7, k8);
        r0.z = qnet_eval1(xb.x, xb.y, k0, k1, k2, k3, k4, k5, k6, k7, k8);
        r0.w = qnet_eval1(xb.z, xb.w, k0, k1, k2, k3, k4, k5, k6, k7, k8);
        r1.x = qnet_eval1(xc.x, xc.y, k0, k1, k2, k3, k4, k5, k6, k7, k8);
        r1.y = qnet_eval1(xc.z, xc.w, k0, k1, k2, k3, k4, k5, k6, k7, k8);
        r1.z = qnet_eval1(xd.x, xd.y, k0, k1, k2, k3, k4, k5, k6, k7, k8);
        r1.w = qnet_eval1(xd.z, xd.w, k0, k1, k2, k3, k4, k5, k6, k7, k8);
        __builtin_nontemporal_store(r0, &out[q0 + 0]);
        __builtin_nontemporal_store(r1, &out[q0 + 1]);
    } else if (tail) {                        // odd tail quad
        vfloat4 r0;
        r0.x = qnet_eval1(xa.x, xa.y, k0, k1, k2, k3, k4, k5, k6, k7, k8);
        r0.y = qnet_eval1(xa.z, xa.w, k0, k1, k2, k3, k4, k5, k6, k7, k8);
        r0.z = qnet_eval1(xb.x, xb.y, k0, k1, k2, k3, k4, k5, k6, k7, k8);
        r0.w = qnet_eval1(xb.z, xb.w, k0, k1, k2, k3, k4, k5, k6, k7, k8);
        __builtin_nontemporal_store(r0, &out[q0]);
    }
}

extern "C" void kernel_launch(void* const* d_in, const int* in_sizes, int n_in,
                              void* d_out, int out_size, void* d_ws, size_t ws_size,
                              hipStream_t stream) {
    const float* x = (const float*)d_in[0];    // [B, 2] float32
    const float* w = (const float*)d_in[1];    // [N_LAYERS, 2] float32

    int nquads = in_sizes[0] / 8;              // in_sizes[0] = #floats = 2*B; quad = 4 samples
    int nthreads = (nquads + 1) / 2;           // 8 samples per thread
    int blocks = (nthreads + 255) / 256;
    qnet_fused_kernel<<<blocks, 256, 0, stream>>>(
        (const float4*)x, w, (vfloat4*)d_out, nquads);
}